// Round 1
// baseline (21063.005 us; speedup 1.0000x reference)
//
#include <hip/hip_runtime.h>
#include <hip/hip_bf16.h>
#include <math.h>

// Problem constants (from reference)
#define L   8
#define H   1024
#define NH  16
#define KVH 8
#define HD  128
#define FF  3072
#define V   32000
#define MAXSEQ 2048
#define S   1024
#define EPS 1e-6f
#define G   (NH / KVH)   // 2

typedef _Float16 f16;
typedef __attribute__((ext_vector_type(8))) _Float16 f16x8;
typedef __attribute__((ext_vector_type(4))) float f32x4;

// ---------------- embed: hidden[s][h] = u8[id][h]*scale[id] + zp[id] ----------------
// NOTE: harness delivers ALL integer inputs as int32, including the uint8 embed table.
__global__ __launch_bounds__(256) void embed_kernel(const int* __restrict__ ids,
                                                    const int* __restrict__ ed,
                                                    const float* __restrict__ scale,
                                                    const float* __restrict__ zp,
                                                    float* __restrict__ hidden)
{
    const int s = blockIdx.x;
    const int id = ids[s];
    const float sc = scale[id];
    const float z  = zp[id];
    const int* row = ed + (size_t)id * H;
    float* out = hidden + (size_t)s * H;
    for (int h = threadIdx.x; h < H; h += 256)
        out[h] = (float)row[h] * sc + z;
}

// ---------------- RMSNorm over H=1024 columns, one block per row ----------------
__global__ __launch_bounds__(256) void rmsnorm_kernel(const float* __restrict__ x,
                                                      const float* __restrict__ w,
                                                      float* __restrict__ out)
{
    const int row = blockIdx.x;
    const float* xp = x + (size_t)row * H;
    float s = 0.f;
    for (int c = threadIdx.x; c < H; c += 256) { float v = xp[c]; s += v * v; }
    __shared__ float red[256];
    red[threadIdx.x] = s; __syncthreads();
    for (int st = 128; st > 0; st >>= 1) {
        if (threadIdx.x < st) red[threadIdx.x] += red[threadIdx.x + st];
        __syncthreads();
    }
    const float inv = 1.0f / sqrtf(red[0] / (float)H + EPS);
    float* op = out + (size_t)row * H;
    for (int c = threadIdx.x; c < H; c += 256)
        op[c] = w[c] * (xp[c] * inv);
}

// ---------------- transpose+convert: in fp32 [K][N] -> out f16 [N][K] ----------------
// 32x32 LDS tile, coalesced read and write. K,N multiples of 32.
__global__ __launch_bounds__(256) void transpose_f16_kernel(const float* __restrict__ in,
                                                            f16* __restrict__ out,
                                                            int K, int N)
{
    __shared__ float tile[32][33];
    const int tx = threadIdx.x & 31, ty = threadIdx.x >> 5;   // 32 x 8
    const int n0 = blockIdx.x * 32, k0 = blockIdx.y * 32;
#pragma unroll
    for (int r = 0; r < 32; r += 8)
        tile[ty + r][tx] = in[(size_t)(k0 + ty + r) * N + n0 + tx];
    __syncthreads();
#pragma unroll
    for (int r = 0; r < 32; r += 8)
        out[(size_t)(n0 + ty + r) * K + k0 + tx] = (f16)tile[tx][ty + r];
}

// ---------------- MFMA f16 GEMM: C[M,N] (+)= A[M,K] @ B[K,N] ----------------
// A: fp32 row-major (converted to f16 during LDS staging).
// Bt: f16 [N][K] (pre-transposed weight panel).
// 64x64 tile, K-step 32 (one mfma_f32_16x16x32_f16 per fragment pair).
// 4 waves, wave w owns 32x32 quadrant (wm,wn) = ((w>>1)*32, (w&1)*32), 2x2 frags.
// LDS rows padded to 40 f16 = 80 B: 16B-aligned ds_read_b128, ~2-way banks (free).
__global__ __launch_bounds__(256) void gemm_f16_kernel(const float* __restrict__ A,
                                                       const f16* __restrict__ Bt,
                                                       float* __restrict__ C,
                                                       int M, int N, int K, int addC)
{
    __shared__ __align__(16) f16 As[64][40];
    __shared__ __align__(16) f16 Bs[64][40];
    const int tid  = threadIdx.x;
    const int lane = tid & 63;
    const int wave = tid >> 6;
    const int wm = (wave >> 1) * 32;
    const int wn = (wave & 1) * 32;
    // staging assignment: thread t loads 8 contiguous elems of row (t>>2), colgroup (t&3)*8
    const int srow = tid >> 2;
    const int scol = (tid & 3) * 8;
    const float* Ab = A  + (size_t)(blockIdx.y * 64 + srow) * K + scol;
    const f16*   Bb = Bt + (size_t)(blockIdx.x * 64 + srow) * K + scol;
    const int l15 = lane & 15;
    const int l8  = (lane >> 4) * 8;   // k-subgroup offset within fragment
    f32x4 acc[2][2] = {};
    for (int k0 = 0; k0 < K; k0 += 32) {
        // stage A (fp32 -> f16) and B (f16 direct)
        float4 a0 = *(const float4*)(Ab + k0);
        float4 a1 = *(const float4*)(Ab + k0 + 4);
        f16x8 av = { (f16)a0.x, (f16)a0.y, (f16)a0.z, (f16)a0.w,
                     (f16)a1.x, (f16)a1.y, (f16)a1.z, (f16)a1.w };
        *(f16x8*)&As[srow][scol] = av;
        *(f16x8*)&Bs[srow][scol] = *(const f16x8*)(Bb + k0);
        __syncthreads();
        // fragments: A lane layout row=l&15, k=(l>>4)*8+j ; B col=l&15, k=(l>>4)*8+j
        f16x8 af0 = *(const f16x8*)&As[wm      + l15][l8];
        f16x8 af1 = *(const f16x8*)&As[wm + 16 + l15][l8];
        f16x8 bf0 = *(const f16x8*)&Bs[wn      + l15][l8];
        f16x8 bf1 = *(const f16x8*)&Bs[wn + 16 + l15][l8];
        acc[0][0] = __builtin_amdgcn_mfma_f32_16x16x32_f16(af0, bf0, acc[0][0], 0, 0, 0);
        acc[0][1] = __builtin_amdgcn_mfma_f32_16x16x32_f16(af0, bf1, acc[0][1], 0, 0, 0);
        acc[1][0] = __builtin_amdgcn_mfma_f32_16x16x32_f16(af1, bf0, acc[1][0], 0, 0, 0);
        acc[1][1] = __builtin_amdgcn_mfma_f32_16x16x32_f16(af1, bf1, acc[1][1], 0, 0, 0);
        __syncthreads();
    }
    // C/D layout (m89): col = lane&15, row = (lane>>4)*4 + j
    const int r0 = (lane >> 4) * 4;
#pragma unroll
    for (int mi = 0; mi < 2; mi++)
#pragma unroll
        for (int ni = 0; ni < 2; ni++) {
            float* cp = C + (size_t)(blockIdx.y * 64 + wm + mi * 16 + r0) * N
                          + blockIdx.x * 64 + wn + ni * 16 + l15;
            if (addC) {
#pragma unroll
                for (int j = 0; j < 4; j++) cp[(size_t)j * N] += acc[mi][ni][j];
            } else {
#pragma unroll
                for (int j = 0; j < 4; j++) cp[(size_t)j * N]  = acc[mi][ni][j];
            }
        }
}

// ------- fused per-(s,head) RMSNorm (over HD) + RoPE, in place. nheads = NH or KVH ----
__global__ __launch_bounds__(128) void qknorm_rope_kernel(float* __restrict__ x,
                                                          const float* __restrict__ nw,
                                                          const float* __restrict__ cose,
                                                          const float* __restrict__ sine,
                                                          int nheads)
{
    const int row = blockIdx.x;          // s*nheads + head
    const int s = row / nheads;
    const int d = threadIdx.x;           // 0..127
    float* xp = x + (size_t)row * HD;
    const float v = xp[d];
    __shared__ float red[128];
    red[d] = v * v; __syncthreads();
    for (int st = 64; st > 0; st >>= 1) {
        if (d < st) red[d] += red[d + st];
        __syncthreads();
    }
    const float inv = 1.0f / sqrtf(red[0] / (float)HD + EPS);
    const float xn = nw[d] * (v * inv);
    __shared__ float xs[128];
    xs[d] = xn; __syncthreads();
    const float rot = (d < 64) ? -xs[d + 64] : xs[d - 64];
    const float c  = cose[(size_t)s * HD + d];
    const float sn = sine[(size_t)s * HD + d];
    xp[d] = xn * c + rot * sn;
}

// ---------------- fused causal attention: one block per (head, q-row) ----------------
// q: (S, NH, HD), k,v: (S, KVH, HD), ao: (S, NH, HD)
__global__ __launch_bounds__(256) void attn_kernel(const float* __restrict__ q,
                                                   const float* __restrict__ k,
                                                   const float* __restrict__ v,
                                                   float* __restrict__ ao)
{
    const int h = blockIdx.x;    // 0..NH-1
    const int sq = blockIdx.y;   // 0..S-1
    const int kvh = h >> 1;      // G = 2
    const int tid = threadIdx.x;
    __shared__ __align__(16) float qs[HD];
    __shared__ float sc[S];
    __shared__ float red[256];
    __shared__ float gmaxs, gsums;
    if (tid < HD) qs[tid] = q[((size_t)sq * NH + h) * HD + tid];
    __syncthreads();
    const int n = sq + 1;        // masked keys (sk>sq) underflow to 0 in fp32 exp — skip them
    for (int sk = tid; sk < n; sk += 256) {
        const float4* kp = (const float4*)(k + ((size_t)sk * KVH + kvh) * HD);
        float acc = 0.f;
#pragma unroll
        for (int d4 = 0; d4 < HD / 4; d4++) {
            float4 kv = kp[d4];
            float4 qv = *(const float4*)(qs + d4 * 4);
            acc += qv.x * kv.x + qv.y * kv.y + qv.z * kv.z + qv.w * kv.w;
        }
        sc[sk] = acc;
    }
    __syncthreads();
    // max
    float m = -3.0e38f;
    for (int sk = tid; sk < n; sk += 256) m = fmaxf(m, sc[sk]);
    red[tid] = m; __syncthreads();
    for (int st = 128; st > 0; st >>= 1) {
        if (tid < st) red[tid] = fmaxf(red[tid], red[tid + st]);
        __syncthreads();
    }
    if (tid == 0) gmaxs = red[0];
    __syncthreads();
    const float gmax = gmaxs;
    float lsum = 0.f;
    for (int sk = tid; sk < n; sk += 256) {
        float p = expf(sc[sk] - gmax);
        sc[sk] = p;
        lsum += p;
    }
    __syncthreads();   // all sc writes done before PV reads
    red[tid] = lsum; __syncthreads();
    for (int st = 128; st > 0; st >>= 1) {
        if (tid < st) red[tid] += red[tid + st];
        __syncthreads();
    }
    if (tid == 0) gsums = red[0];
    __syncthreads();
    const float inv = 1.0f / gsums;
    // PV: 2 partitions over sk, 128 dims each
    const int d = tid & 127, half = tid >> 7;
    float acc = 0.f;
    for (int sk = half; sk < n; sk += 2)
        acc += sc[sk] * v[((size_t)sk * KVH + kvh) * HD + d];
    red[tid] = acc; __syncthreads();
    if (tid < 128)
        ao[((size_t)sq * NH + h) * HD + tid] = (red[tid] + red[tid + 128]) * inv;
}

// ---------------- silu(gate) * up, in place into gate ----------------
__global__ __launch_bounds__(256) void silumul_kernel(float* __restrict__ g,
                                                      const float* __restrict__ u, int n)
{
    const int i = blockIdx.x * 256 + threadIdx.x;
    if (i < n) {
        float x = g[i];
        g[i] = (x / (1.0f + expf(-x))) * u[i];
    }
}

// ---------------- logits: out[v] = h(1024) . W[:,v], W row-major (H, V) ----------------
__global__ __launch_bounds__(256) void logits_kernel(const float* __restrict__ h,
                                                     const float* __restrict__ W,
                                                     float* __restrict__ out)
{
    __shared__ float hs[H];
    for (int i = threadIdx.x; i < H; i += 256) hs[i] = h[i];
    __syncthreads();
    const int v = blockIdx.x * 256 + threadIdx.x;
    float acc = 0.f;
    for (int kk = 0; kk < H; kk++)
        acc += hs[kk] * W[(size_t)kk * V + v];
    out[v] = acc;
}

// ---------------- argmax over V, first-max tie-break ----------------
__global__ __launch_bounds__(1024) void argmax_kernel(const float* __restrict__ x,
                                                      int* __restrict__ out)
{
    const int tid = threadIdx.x;
    float best = -3.0e38f; int bi = V;
    for (int v = tid; v < V; v += 1024) {
        float val = x[v];
        if (val > best) { best = val; bi = v; }
    }
    __shared__ float bv[1024];
    __shared__ int bidx[1024];
    bv[tid] = best; bidx[tid] = bi; __syncthreads();
    for (int st = 512; st > 0; st >>= 1) {
        if (tid < st) {
            if (bv[tid + st] > bv[tid] ||
                (bv[tid + st] == bv[tid] && bidx[tid + st] < bidx[tid])) {
                bv[tid] = bv[tid + st]; bidx[tid] = bidx[tid + st];
            }
        }
        __syncthreads();
    }
    if (tid == 0) out[0] = bidx[0];
}

extern "C" void kernel_launch(void* const* d_in, const int* in_sizes, int n_in,
                              void* d_out, int out_size, void* d_ws, size_t ws_size,
                              hipStream_t stream)
{
    // inputs per setup_inputs() order
    const int*   input_ids    = (const int*)d_in[2];
    const int*   embed_data   = (const int*)d_in[5];   // uint8 table, delivered as int32
    const float* zero_point   = (const float*)d_in[6];
    const float* scale        = (const float*)d_in[7];
    const float* cos_emb      = (const float*)d_in[8]; // (1, MAX, HD); past_len = 0
    const float* sin_emb      = (const float*)d_in[9];
    const float* ln1_w        = (const float*)d_in[10];
    const float* q_w          = (const float*)d_in[11];
    const float* k_w          = (const float*)d_in[12];
    const float* v_w          = (const float*)d_in[13];
    const float* q_norm_w     = (const float*)d_in[14];
    const float* k_norm_w     = (const float*)d_in[15];
    const float* o_w          = (const float*)d_in[16];
    const float* ln2_w        = (const float*)d_in[17];
    const float* gate_w       = (const float*)d_in[18];
    const float* up_w         = (const float*)d_in[19];
    const float* down_w       = (const float*)d_in[20];
    const float* final_norm_w = (const float*)d_in[21];
    const float* lm_head_w    = (const float*)d_in[22];

    // workspace layout (floats); ~39 MB total.
    // attention buffers (q/k/v/ao) and MLP buffers (gate/up) are live in disjoint
    // phases -> alias them over one 6M-float region.
    const size_t M1 = 1024 * 1024;
    float* ws     = (float*)d_ws;
    float* hidden = ws;              // 1M floats
    float* hn     = ws + M1;         // 1M
    float* big    = ws + 2 * M1;     // 6M shared region
    float* qbuf   = big;             // 2M   (S*NH*HD)
    float* kbuf   = big + 2 * M1;    // 1M   (S*KVH*HD)
    float* vbuf   = big + 3 * M1;    // 1M
    float* aobuf  = big + 4 * M1;    // 2M
    float* gbuf   = big;             // 3M   (S*FF) aliases q+k
    float* ubuf   = big + 3 * M1;    // 3M   aliases v+ao
    float* lbuf   = ws + 8 * M1;     // V floats
    // f16 transposed-weight panel: max N*K = 3072*1024 f16 = 1.5M floats
    f16*   wt16   = (f16*)(ws + 8 * M1 + 65536);

    embed_kernel<<<S, 256, 0, stream>>>(input_ids, embed_data, scale, zero_point, hidden);

    for (int i = 0; i < L; i++) {
        rmsnorm_kernel<<<S, 256, 0, stream>>>(hidden, ln1_w + (size_t)i * H, hn);

        // q-proj: (S,H) @ (H, 2048)
        transpose_f16_kernel<<<dim3((NH * HD) / 32, H / 32), 256, 0, stream>>>(
            q_w + (size_t)i * H * NH * HD, wt16, H, NH * HD);
        gemm_f16_kernel<<<dim3((NH * HD) / 64, S / 64), 256, 0, stream>>>(
            hn, wt16, qbuf, S, NH * HD, H, 0);
        // k-proj
        transpose_f16_kernel<<<dim3((KVH * HD) / 32, H / 32), 256, 0, stream>>>(
            k_w + (size_t)i * H * KVH * HD, wt16, H, KVH * HD);
        gemm_f16_kernel<<<dim3((KVH * HD) / 64, S / 64), 256, 0, stream>>>(
            hn, wt16, kbuf, S, KVH * HD, H, 0);
        // v-proj
        transpose_f16_kernel<<<dim3((KVH * HD) / 32, H / 32), 256, 0, stream>>>(
            v_w + (size_t)i * H * KVH * HD, wt16, H, KVH * HD);
        gemm_f16_kernel<<<dim3((KVH * HD) / 64, S / 64), 256, 0, stream>>>(
            hn, wt16, vbuf, S, KVH * HD, H, 0);

        qknorm_rope_kernel<<<S * NH, 128, 0, stream>>>(
            qbuf, q_norm_w + (size_t)i * HD, cos_emb, sin_emb, NH);
        qknorm_rope_kernel<<<S * KVH, 128, 0, stream>>>(
            kbuf, k_norm_w + (size_t)i * HD, cos_emb, sin_emb, KVH);

        attn_kernel<<<dim3(NH, S), 256, 0, stream>>>(qbuf, kbuf, vbuf, aobuf);

        // o-proj: (S, 2048) @ (2048, H), accumulate into hidden
        transpose_f16_kernel<<<dim3(H / 32, (NH * HD) / 32), 256, 0, stream>>>(
            o_w + (size_t)i * NH * HD * H, wt16, NH * HD, H);
        gemm_f16_kernel<<<dim3(H / 64, S / 64), 256, 0, stream>>>(
            aobuf, wt16, hidden, S, H, NH * HD, 1);

        rmsnorm_kernel<<<S, 256, 0, stream>>>(hidden, ln2_w + (size_t)i * H, hn);

        // gate
        transpose_f16_kernel<<<dim3(FF / 32, H / 32), 256, 0, stream>>>(
            gate_w + (size_t)i * H * FF, wt16, H, FF);
        gemm_f16_kernel<<<dim3(FF / 64, S / 64), 256, 0, stream>>>(
            hn, wt16, gbuf, S, FF, H, 0);
        // up
        transpose_f16_kernel<<<dim3(FF / 32, H / 32), 256, 0, stream>>>(
            up_w + (size_t)i * H * FF, wt16, H, FF);
        gemm_f16_kernel<<<dim3(FF / 64, S / 64), 256, 0, stream>>>(
            hn, wt16, ubuf, S, FF, H, 0);

        silumul_kernel<<<(S * FF) / 256, 256, 0, stream>>>(gbuf, ubuf, S * FF);

        // down: (S, FF) @ (FF, H), accumulate into hidden
        transpose_f16_kernel<<<dim3(H / 32, FF / 32), 256, 0, stream>>>(
            down_w + (size_t)i * FF * H, wt16, FF, H);
        gemm_f16_kernel<<<dim3(H / 64, S / 64), 256, 0, stream>>>(
            gbuf, wt16, hidden, S, H, FF, 1);
    }

    rmsnorm_kernel<<<1, 256, 0, stream>>>(hidden + (size_t)(S - 1) * H, final_norm_w, hn);
    logits_kernel<<<V / 256, 256, 0, stream>>>(hn, lm_head_w, lbuf);
    argmax_kernel<<<1, 1024, 0, stream>>>(lbuf, (int*)d_out);
}

// Round 2
// 3536.133 us; speedup vs baseline: 5.9565x; 5.9565x over previous
//
#include <hip/hip_runtime.h>
#include <hip/hip_bf16.h>
#include <math.h>

// Problem constants (from reference)
#define L   8
#define H   1024
#define NH  16
#define KVH 8
#define HD  128
#define FF  3072
#define V   32000
#define MAXSEQ 2048
#define S   1024
#define EPS 1e-6f
#define G   (NH / KVH)   // 2

typedef _Float16 f16;
typedef __attribute__((ext_vector_type(4))) _Float16 f16x4;
typedef __attribute__((ext_vector_type(8))) _Float16 f16x8;
typedef __attribute__((ext_vector_type(4))) float f32x4;

// ---------------- embed: hidden[s][h] = u8[id][h]*scale[id] + zp[id] ----------------
// NOTE: harness delivers ALL integer inputs as int32, including the uint8 embed table.
__global__ __launch_bounds__(256) void embed_kernel(const int* __restrict__ ids,
                                                    const int* __restrict__ ed,
                                                    const float* __restrict__ scale,
                                                    const float* __restrict__ zp,
                                                    float* __restrict__ hidden)
{
    const int s = blockIdx.x;
    const int id = ids[s];
    const float sc = scale[id];
    const float z  = zp[id];
    const int* row = ed + (size_t)id * H;
    float* out = hidden + (size_t)s * H;
    for (int h = threadIdx.x; h < H; h += 256)
        out[h] = (float)row[h] * sc + z;
}

// ---------------- RMSNorm over H=1024 columns, one block per row ----------------
__global__ __launch_bounds__(256) void rmsnorm_kernel(const float* __restrict__ x,
                                                      const float* __restrict__ w,
                                                      float* __restrict__ out)
{
    const int row = blockIdx.x;
    const float* xp = x + (size_t)row * H;
    float s = 0.f;
    for (int c = threadIdx.x; c < H; c += 256) { float v = xp[c]; s += v * v; }
    __shared__ float red[256];
    red[threadIdx.x] = s; __syncthreads();
    for (int st = 128; st > 0; st >>= 1) {
        if (threadIdx.x < st) red[threadIdx.x] += red[threadIdx.x + st];
        __syncthreads();
    }
    const float inv = 1.0f / sqrtf(red[0] / (float)H + EPS);
    float* op = out + (size_t)row * H;
    for (int c = threadIdx.x; c < H; c += 256)
        op[c] = w[c] * (xp[c] * inv);
}

// ---------------- transpose+convert: in fp32 [K][N] -> out f16 [N][K] ----------------
__global__ __launch_bounds__(256) void transpose_f16_kernel(const float* __restrict__ in,
                                                            f16* __restrict__ out,
                                                            int K, int N)
{
    __shared__ float tile[32][33];
    const int tx = threadIdx.x & 31, ty = threadIdx.x >> 5;   // 32 x 8
    const int n0 = blockIdx.x * 32, k0 = blockIdx.y * 32;
#pragma unroll
    for (int r = 0; r < 32; r += 8)
        tile[ty + r][tx] = in[(size_t)(k0 + ty + r) * N + n0 + tx];
    __syncthreads();
#pragma unroll
    for (int r = 0; r < 32; r += 8)
        out[(size_t)(n0 + ty + r) * K + k0 + tx] = (f16)tile[tx][ty + r];
}

// ---------------- MFMA f16 GEMM: C[M,N] (+)= A[M,K] @ B[K,N] ----------------
// A: fp32 row-major (converted to f16 during LDS staging). Bt: f16 [N][K].
// 64x64 tile, K-step 32. 4 waves, wave w owns 32x32 quadrant, 2x2 frags.
__global__ __launch_bounds__(256) void gemm_f16_kernel(const float* __restrict__ A,
                                                       const f16* __restrict__ Bt,
                                                       float* __restrict__ C,
                                                       int M, int N, int K, int addC)
{
    __shared__ __align__(16) f16 As[64][40];
    __shared__ __align__(16) f16 Bs[64][40];
    const int tid  = threadIdx.x;
    const int lane = tid & 63;
    const int wave = tid >> 6;
    const int wm = (wave >> 1) * 32;
    const int wn = (wave & 1) * 32;
    const int srow = tid >> 2;
    const int scol = (tid & 3) * 8;
    const float* Ab = A  + (size_t)(blockIdx.y * 64 + srow) * K + scol;
    const f16*   Bb = Bt + (size_t)(blockIdx.x * 64 + srow) * K + scol;
    const int l15 = lane & 15;
    const int l8  = (lane >> 4) * 8;
    f32x4 acc[2][2] = {};
    for (int k0 = 0; k0 < K; k0 += 32) {
        float4 a0 = *(const float4*)(Ab + k0);
        float4 a1 = *(const float4*)(Ab + k0 + 4);
        f16x8 av = { (f16)a0.x, (f16)a0.y, (f16)a0.z, (f16)a0.w,
                     (f16)a1.x, (f16)a1.y, (f16)a1.z, (f16)a1.w };
        *(f16x8*)&As[srow][scol] = av;
        *(f16x8*)&Bs[srow][scol] = *(const f16x8*)(Bb + k0);
        __syncthreads();
        f16x8 af0 = *(const f16x8*)&As[wm      + l15][l8];
        f16x8 af1 = *(const f16x8*)&As[wm + 16 + l15][l8];
        f16x8 bf0 = *(const f16x8*)&Bs[wn      + l15][l8];
        f16x8 bf1 = *(const f16x8*)&Bs[wn + 16 + l15][l8];
        acc[0][0] = __builtin_amdgcn_mfma_f32_16x16x32_f16(af0, bf0, acc[0][0], 0, 0, 0);
        acc[0][1] = __builtin_amdgcn_mfma_f32_16x16x32_f16(af0, bf1, acc[0][1], 0, 0, 0);
        acc[1][0] = __builtin_amdgcn_mfma_f32_16x16x32_f16(af1, bf0, acc[1][0], 0, 0, 0);
        acc[1][1] = __builtin_amdgcn_mfma_f32_16x16x32_f16(af1, bf1, acc[1][1], 0, 0, 0);
        __syncthreads();
    }
    const int r0 = (lane >> 4) * 4;
#pragma unroll
    for (int mi = 0; mi < 2; mi++)
#pragma unroll
        for (int ni = 0; ni < 2; ni++) {
            float* cp = C + (size_t)(blockIdx.y * 64 + wm + mi * 16 + r0) * N
                          + blockIdx.x * 64 + wn + ni * 16 + l15;
            if (addC) {
#pragma unroll
                for (int j = 0; j < 4; j++) cp[(size_t)j * N] += acc[mi][ni][j];
            } else {
#pragma unroll
                for (int j = 0; j < 4; j++) cp[(size_t)j * N]  = acc[mi][ni][j];
            }
        }
}

// ------- fused per-(s,head) RMSNorm (over HD) + RoPE, in place. nheads = NH or KVH ----
__global__ __launch_bounds__(128) void qknorm_rope_kernel(float* __restrict__ x,
                                                          const float* __restrict__ nw,
                                                          const float* __restrict__ cose,
                                                          const float* __restrict__ sine,
                                                          int nheads)
{
    const int row = blockIdx.x;          // s*nheads + head
    const int s = row / nheads;
    const int d = threadIdx.x;           // 0..127
    float* xp = x + (size_t)row * HD;
    const float v = xp[d];
    __shared__ float red[128];
    red[d] = v * v; __syncthreads();
    for (int st = 64; st > 0; st >>= 1) {
        if (d < st) red[d] += red[d + st];
        __syncthreads();
    }
    const float inv = 1.0f / sqrtf(red[0] / (float)HD + EPS);
    const float xn = nw[d] * (v * inv);
    __shared__ float xs[128];
    xs[d] = xn; __syncthreads();
    const float rot = (d < 64) ? -xs[d + 64] : xs[d - 64];
    const float c  = cose[(size_t)s * HD + d];
    const float sn = sine[(size_t)s * HD + d];
    xp[d] = xn * c + rot * sn;
}

// ---------------- MFMA flash attention ----------------
// q: (S, NH, HD) fp32 (post norm+rope), k,v: (S, KVH, HD) fp32, ao: (S, NH, HD) fp32.
// Block = (kvh, 32-row q-tile). Waves 0,1 -> head 2*kvh rows [0,16)/[16,32);
// waves 2,3 -> head 2*kvh+1. K/V tiles of 32 keys staged once in LDS for both heads.
// Online softmax per q-row; scores live in 16-lane groups (C layout col=key).
__global__ __launch_bounds__(256) void flash_attn_kernel(const float* __restrict__ q,
                                                         const float* __restrict__ k,
                                                         const float* __restrict__ v,
                                                         float* __restrict__ ao)
{
    __shared__ __align__(16) f16 Ks[32][136];   // keys row-major, pad 272B rows
    __shared__ __align__(16) f16 Vt[128][40];   // V transposed [d][key], pad 80B rows
    __shared__ __align__(16) f16 Pl[4][16][40]; // per-wave P buffer
    const int kvh = blockIdx.x;
    const int qt  = blockIdx.y;
    const int qbase = qt * 32;
    const int tid  = threadIdx.x;
    const int wave = tid >> 6;
    const int lane = tid & 63;
    const int head = kvh * 2 + (wave >> 1);
    const int wrow = qbase + (wave & 1) * 16;   // first q row of this wave's band
    const int l15 = lane & 15;
    const int lg  = lane >> 4;                  // 0..3

    // Q fragments for this wave's 16 rows, held in registers for the whole kernel.
    f16x8 qf[4];
    {
        const float* qp = q + ((size_t)(wrow + l15) * NH + head) * HD;
#pragma unroll
        for (int ks = 0; ks < 4; ks++) {
            float4 a0 = *(const float4*)(qp + ks * 32 + lg * 8);
            float4 a1 = *(const float4*)(qp + ks * 32 + lg * 8 + 4);
            qf[ks] = (f16x8){ (f16)a0.x, (f16)a0.y, (f16)a0.z, (f16)a0.w,
                              (f16)a1.x, (f16)a1.y, (f16)a1.z, (f16)a1.w };
        }
    }

    f32x4 o[8] = {};                 // O accumulator: col=l15+16*nf, row=lg*4+j
    float m[4]  = { -1e30f, -1e30f, -1e30f, -1e30f };
    float lsum[4] = { 0.f, 0.f, 0.f, 0.f };

    for (int t = 0; t <= qt; ++t) {
        const int k0 = t * 32;
        // ---- stage K (row-major f16) and V (transposed f16) ----
#pragma unroll
        for (int i = 0; i < 4; i++) {
            const int flat = tid + i * 256;     // 1024 float4 = 32 rows x 32 f4
            const int key = flat >> 5;
            const int d4  = flat & 31;
            const size_t base = ((size_t)(k0 + key) * KVH + kvh) * HD + d4 * 4;
            float4 kk = *(const float4*)(k + base);
            *(f16x4*)&Ks[key][d4 * 4] = (f16x4){ (f16)kk.x, (f16)kk.y, (f16)kk.z, (f16)kk.w };
            float4 vv = *(const float4*)(v + base);
            Vt[d4 * 4 + 0][key] = (f16)vv.x;
            Vt[d4 * 4 + 1][key] = (f16)vv.y;
            Vt[d4 * 4 + 2][key] = (f16)vv.z;
            Vt[d4 * 4 + 3][key] = (f16)vv.w;
        }
        __syncthreads();

        // ---- QK^T: S[16 rows][32 keys] via 2 col-frags x 4 k-steps ----
        f32x4 s0 = {}, s1 = {};
#pragma unroll
        for (int ks = 0; ks < 4; ks++) {
            f16x8 kf0 = *(const f16x8*)&Ks[l15][ks * 32 + lg * 8];
            f16x8 kf1 = *(const f16x8*)&Ks[l15 + 16][ks * 32 + lg * 8];
            s0 = __builtin_amdgcn_mfma_f32_16x16x32_f16(qf[ks], kf0, s0, 0, 0, 0);
            s1 = __builtin_amdgcn_mfma_f32_16x16x32_f16(qf[ks], kf1, s1, 0, 0, 0);
        }

        // ---- causal mask on the diagonal tile ----
        if (t == qt) {
#pragma unroll
            for (int j = 0; j < 4; j++) {
                const int row = wrow + lg * 4 + j;
                if (k0 + l15      > row) s0[j] = -1e30f;
                if (k0 + l15 + 16 > row) s1[j] = -1e30f;
            }
        }

        // ---- online softmax (rows live across the 16 lanes of each lane-group) ----
        float tm[4], sc[4], p0[4], p1[4], ts[4];
#pragma unroll
        for (int j = 0; j < 4; j++) tm[j] = fmaxf(s0[j], s1[j]);
#pragma unroll
        for (int d = 1; d < 16; d <<= 1)
#pragma unroll
            for (int j = 0; j < 4; j++) tm[j] = fmaxf(tm[j], __shfl_xor(tm[j], d));
#pragma unroll
        for (int j = 0; j < 4; j++) {
            const float mn = fmaxf(m[j], tm[j]);
            sc[j] = expf(m[j] - mn);
            m[j] = mn;
            p0[j] = expf(s0[j] - mn);
            p1[j] = expf(s1[j] - mn);
            ts[j] = p0[j] + p1[j];
        }
#pragma unroll
        for (int d = 1; d < 16; d <<= 1)
#pragma unroll
            for (int j = 0; j < 4; j++) ts[j] += __shfl_xor(ts[j], d);
#pragma unroll
        for (int j = 0; j < 4; j++) lsum[j] = lsum[j] * sc[j] + ts[j];
#pragma unroll
        for (int nf = 0; nf < 8; nf++)
#pragma unroll
            for (int j = 0; j < 4; j++) o[nf][j] *= sc[j];

        // ---- P -> LDS (transpose to A-frag layout), then PV ----
#pragma unroll
        for (int j = 0; j < 4; j++) {
            Pl[wave][lg * 4 + j][l15]      = (f16)p0[j];
            Pl[wave][lg * 4 + j][l15 + 16] = (f16)p1[j];
        }
        f16x8 pa = *(const f16x8*)&Pl[wave][l15][lg * 8];
#pragma unroll
        for (int nf = 0; nf < 8; nf++) {
            f16x8 vf = *(const f16x8*)&Vt[l15 + 16 * nf][lg * 8];
            o[nf] = __builtin_amdgcn_mfma_f32_16x16x32_f16(pa, vf, o[nf], 0, 0, 0);
        }
        __syncthreads();   // before next tile overwrites Ks/Vt
    }

    // ---- epilogue: normalize and store ----
    float linv[4];
#pragma unroll
    for (int j = 0; j < 4; j++) linv[j] = 1.0f / lsum[j];
#pragma unroll
    for (int nf = 0; nf < 8; nf++)
#pragma unroll
        for (int j = 0; j < 4; j++)
            ao[((size_t)(wrow + lg * 4 + j) * NH + head) * HD + l15 + 16 * nf] =
                o[nf][j] * linv[j];
}

// ---------------- silu(gate) * up, in place into gate ----------------
__global__ __launch_bounds__(256) void silumul_kernel(float* __restrict__ g,
                                                      const float* __restrict__ u, int n)
{
    const int i = blockIdx.x * 256 + threadIdx.x;
    if (i < n) {
        float x = g[i];
        g[i] = (x / (1.0f + expf(-x))) * u[i];
    }
}

// ---------------- logits: out[v] = h(1024) . W[:,v], W row-major (H, V) ----------------
__global__ __launch_bounds__(256) void logits_kernel(const float* __restrict__ h,
                                                     const float* __restrict__ W,
                                                     float* __restrict__ out)
{
    __shared__ float hs[H];
    for (int i = threadIdx.x; i < H; i += 256) hs[i] = h[i];
    __syncthreads();
    const int v = blockIdx.x * 256 + threadIdx.x;
    float acc = 0.f;
    for (int kk = 0; kk < H; kk++)
        acc += hs[kk] * W[(size_t)kk * V + v];
    out[v] = acc;
}

// ---------------- argmax over V, first-max tie-break ----------------
__global__ __launch_bounds__(1024) void argmax_kernel(const float* __restrict__ x,
                                                      int* __restrict__ out)
{
    const int tid = threadIdx.x;
    float best = -3.0e38f; int bi = V;
    for (int v = tid; v < V; v += 1024) {
        float val = x[v];
        if (val > best) { best = val; bi = v; }
    }
    __shared__ float bv[1024];
    __shared__ int bidx[1024];
    bv[tid] = best; bidx[tid] = bi; __syncthreads();
    for (int st = 512; st > 0; st >>= 1) {
        if (tid < st) {
            if (bv[tid + st] > bv[tid] ||
                (bv[tid + st] == bv[tid] && bidx[tid + st] < bidx[tid])) {
                bv[tid] = bv[tid + st]; bidx[tid] = bidx[tid + st];
            }
        }
        __syncthreads();
    }
    if (tid == 0) out[0] = bidx[0];
}

extern "C" void kernel_launch(void* const* d_in, const int* in_sizes, int n_in,
                              void* d_out, int out_size, void* d_ws, size_t ws_size,
                              hipStream_t stream)
{
    // inputs per setup_inputs() order
    const int*   input_ids    = (const int*)d_in[2];
    const int*   embed_data   = (const int*)d_in[5];   // uint8 table, delivered as int32
    const float* zero_point   = (const float*)d_in[6];
    const float* scale        = (const float*)d_in[7];
    const float* cos_emb      = (const float*)d_in[8]; // (1, MAX, HD); past_len = 0
    const float* sin_emb      = (const float*)d_in[9];
    const float* ln1_w        = (const float*)d_in[10];
    const float* q_w          = (const float*)d_in[11];
    const float* k_w          = (const float*)d_in[12];
    const float* v_w          = (const float*)d_in[13];
    const float* q_norm_w     = (const float*)d_in[14];
    const float* k_norm_w     = (const float*)d_in[15];
    const float* o_w          = (const float*)d_in[16];
    const float* ln2_w        = (const float*)d_in[17];
    const float* gate_w       = (const float*)d_in[18];
    const float* up_w         = (const float*)d_in[19];
    const float* down_w       = (const float*)d_in[20];
    const float* final_norm_w = (const float*)d_in[21];
    const float* lm_head_w    = (const float*)d_in[22];

    const size_t M1 = 1024 * 1024;
    float* ws     = (float*)d_ws;
    float* hidden = ws;              // 1M floats
    float* hn     = ws + M1;         // 1M
    float* big    = ws + 2 * M1;     // 6M shared region
    float* qbuf   = big;             // 2M   (S*NH*HD)
    float* kbuf   = big + 2 * M1;    // 1M   (S*KVH*HD)
    float* vbuf   = big + 3 * M1;    // 1M
    float* aobuf  = big + 4 * M1;    // 2M
    float* gbuf   = big;             // 3M   (S*FF) aliases q+k
    float* ubuf   = big + 3 * M1;    // 3M   aliases v+ao
    float* lbuf   = ws + 8 * M1;     // V floats
    f16*   wt16   = (f16*)(ws + 8 * M1 + 65536);   // 1.5M floats max

    embed_kernel<<<S, 256, 0, stream>>>(input_ids, embed_data, scale, zero_point, hidden);

    for (int i = 0; i < L; i++) {
        rmsnorm_kernel<<<S, 256, 0, stream>>>(hidden, ln1_w + (size_t)i * H, hn);

        transpose_f16_kernel<<<dim3((NH * HD) / 32, H / 32), 256, 0, stream>>>(
            q_w + (size_t)i * H * NH * HD, wt16, H, NH * HD);
        gemm_f16_kernel<<<dim3((NH * HD) / 64, S / 64), 256, 0, stream>>>(
            hn, wt16, qbuf, S, NH * HD, H, 0);
        transpose_f16_kernel<<<dim3((KVH * HD) / 32, H / 32), 256, 0, stream>>>(
            k_w + (size_t)i * H * KVH * HD, wt16, H, KVH * HD);
        gemm_f16_kernel<<<dim3((KVH * HD) / 64, S / 64), 256, 0, stream>>>(
            hn, wt16, kbuf, S, KVH * HD, H, 0);
        transpose_f16_kernel<<<dim3((KVH * HD) / 32, H / 32), 256, 0, stream>>>(
            v_w + (size_t)i * H * KVH * HD, wt16, H, KVH * HD);
        gemm_f16_kernel<<<dim3((KVH * HD) / 64, S / 64), 256, 0, stream>>>(
            hn, wt16, vbuf, S, KVH * HD, H, 0);

        qknorm_rope_kernel<<<S * NH, 128, 0, stream>>>(
            qbuf, q_norm_w + (size_t)i * HD, cos_emb, sin_emb, NH);
        qknorm_rope_kernel<<<S * KVH, 128, 0, stream>>>(
            kbuf, k_norm_w + (size_t)i * HD, cos_emb, sin_emb, KVH);

        flash_attn_kernel<<<dim3(KVH, S / 32), 256, 0, stream>>>(qbuf, kbuf, vbuf, aobuf);

        transpose_f16_kernel<<<dim3(H / 32, (NH * HD) / 32), 256, 0, stream>>>(
            o_w + (size_t)i * NH * HD * H, wt16, NH * HD, H);
        gemm_f16_kernel<<<dim3(H / 64, S / 64), 256, 0, stream>>>(
            aobuf, wt16, hidden, S, H, NH * HD, 1);

        rmsnorm_kernel<<<S, 256, 0, stream>>>(hidden, ln2_w + (size_t)i * H, hn);

        transpose_f16_kernel<<<dim3(FF / 32, H / 32), 256, 0, stream>>>(
            gate_w + (size_t)i * H * FF, wt16, H, FF);
        gemm_f16_kernel<<<dim3(FF / 64, S / 64), 256, 0, stream>>>(
            hn, wt16, gbuf, S, FF, H, 0);
        transpose_f16_kernel<<<dim3(FF / 32, H / 32), 256, 0, stream>>>(
            up_w + (size_t)i * H * FF, wt16, H, FF);
        gemm_f16_kernel<<<dim3(FF / 64, S / 64), 256, 0, stream>>>(
            hn, wt16, ubuf, S, FF, H, 0);

        silumul_kernel<<<(S * FF) / 256, 256, 0, stream>>>(gbuf, ubuf, S * FF);

        transpose_f16_kernel<<<dim3(H / 32, FF / 32), 256, 0, stream>>>(
            down_w + (size_t)i * FF * H, wt16, FF, H);
        gemm_f16_kernel<<<dim3(H / 64, S / 64), 256, 0, stream>>>(
            gbuf, wt16, hidden, S, H, FF, 1);
    }

    rmsnorm_kernel<<<1, 256, 0, stream>>>(hidden + (size_t)(S - 1) * H, final_norm_w, hn);
    logits_kernel<<<V / 256, 256, 0, stream>>>(hn, lm_head_w, lbuf);
    argmax_kernel<<<1, 1024, 0, stream>>>(lbuf, (int*)d_out);
}